// Round 9
// baseline (225.654 us; speedup 1.0000x reference)
//
#include <hip/hip_runtime.h>
#include <hip/hip_fp16.h>
#include <math.h>

#define NN 100000
#define NE 1600000
#define KF 48
#define NEDGE_ALL (2 * NE)

#define BKT_NODES 64                     // nodes per bucket (dst >> 6)  [r20: 128 -> 64]
#define NBKT_PER  1563                   // ceil(100000/64)
#define NBKT      3126                   // pos buckets then neg buckets
#define PACK_EPB  16384                  // edges per pack block
#define STG_HALF  8192                   // LDS staging half-size (2 passes, 32 KB)
#define NPB       196                    // pack blocks = ceil(3.2M / 16384)
#define OTT       200                    // offTT row stride (>= NPB, even)
#define CAP2      1536                   // per-bucket srt capacity (mean 1024 + >8 sigma)
#define KSTG      6                      // staging registers per thread (6*256 >= CAP2)

typedef _Float16 half2v __attribute__((ext_vector_type(2)));
typedef _Float16 half4v __attribute__((ext_vector_type(4)));
typedef _Float16 half8v __attribute__((ext_vector_type(8)));

#if defined(__has_builtin)
#if __has_builtin(__builtin_amdgcn_fdot2)
#define HAVE_FDOT2 1
#endif
#endif

__device__ __forceinline__ void acc_pair(float& ax, float& ay, half2v v)
{
#ifdef HAVE_FDOT2
    ax = __builtin_amdgcn_fdot2(v, (half2v){(_Float16)1.f, (_Float16)0.f}, ax, false);
    ay = __builtin_amdgcn_fdot2(v, (half2v){(_Float16)0.f, (_Float16)1.f}, ay, false);
#else
    ax += (float)v.x;
    ay += (float)v.y;
#endif
}

// ------ phase 1: fused z-GEMM + LDS-sorted pack, writing offTT (transposed) --------
// r20: bucket granule 128 -> 64 nodes (dst>>6, 3126 buckets). Histogram 12.5 KB,
// scan 8-compressed to 391 (same H-S width as before). Everything else is the
// r8 structure (16K edge granule, two-pass 32 KB staging, direct offTT write).
__global__ __launch_bounds__(512) void pack_kernel(
    const float* __restrict__ x,
    const int* __restrict__ ei_pos,
    const int* __restrict__ ei_neg,
    const float* __restrict__ W1,        // [144,16] row-major
    const float* __restrict__ b1,        // [16]
    unsigned short* __restrict__ offTT,  // [NBKT+2][OTT]: offTT[b][r] = start of bucket b in block r
    unsigned* __restrict__ plist,        // [NPB * PACK_EPB]
    float* __restrict__ za,              // [NN*16] fp32 (x@W1a + b1)
    __half* __restrict__ zbh,            // [(NN+2)*16] fp16 (x@W1b) + zero sentinels
    __half* __restrict__ zch)            // [(NN+2)*16] fp16 (x@W1c) + zero sentinels
{
    __shared__ int cnt[NBKT];            // 12.5 KB hist -> becomes cursor
    __shared__ int ps[391];              // 1.6 KB 8-compressed scan
    __shared__ unsigned stage[STG_HALF]; // 32 KB sorted staging (half-block)
    __shared__ float sW1[144 * 16];      // 9.2 KB weights (broadcast reads)
    __shared__ float sb1[16];

    const int t = threadIdx.x;
    for (int i = t; i < 144 * 16; i += 512) sW1[i] = W1[i];
    if (t < 16) sb1[t] = b1[t];
    for (int i = t; i < NBKT; i += 512) cnt[i] = 0;
    __syncthreads();

    // --- fused z-GEMM: one thread per node, exact cover (196*512 = 100352) ---
    {
        const int n = blockIdx.x * 512 + t;
        if (n < NN + 2) {
            float aA[16], aB[16], aC[16];
#pragma unroll
            for (int j = 0; j < 16; ++j) { aA[j] = sb1[j]; aB[j] = 0.f; aC[j] = 0.f; }
            if (n < NN) {
                const float4* __restrict__ x4 = (const float4*)(x + (long)n * KF);
                for (int i4 = 0; i4 < 12; ++i4) {
                    float4 v = x4[i4];
                    float vv[4] = {v.x, v.y, v.z, v.w};
#pragma unroll
                    for (int c = 0; c < 4; ++c) {
                        const int f = i4 * 4 + c;
                        const float* wA = &sW1[f * 16];
                        const float* wB = &sW1[(48 + f) * 16];
                        const float* wC = &sW1[(96 + f) * 16];
                        const float s = vv[c];
#pragma unroll
                        for (int j = 0; j < 16; ++j) {
                            aA[j] += s * wA[j];
                            aB[j] += s * wB[j];
                            aC[j] += s * wC[j];
                        }
                    }
                }
                float4* za4 = (float4*)(za + (long)n * 16);
#pragma unroll
                for (int j4 = 0; j4 < 4; ++j4)
                    za4[j4] = make_float4(aA[4*j4], aA[4*j4+1], aA[4*j4+2], aA[4*j4+3]);
            }
            half8v hb0, hb1, hc0, hc1;
#pragma unroll
            for (int j = 0; j < 8; ++j) {
                hb0[j] = (_Float16)aB[j];     hb1[j] = (_Float16)aB[8 + j];
                hc0[j] = (_Float16)aC[j];     hc1[j] = (_Float16)aC[8 + j];
            }
            half8v* zb8 = (half8v*)zbh;
            half8v* zc8 = (half8v*)zch;
            zb8[(long)n * 2 + 0] = hb0;  zb8[(long)n * 2 + 1] = hb1;
            zc8[(long)n * 2 + 0] = hc0;  zc8[(long)n * 2 + 1] = hc1;
        }
    }

    unsigned pk[32];
    int bk[32];
    const int blockBase = blockIdx.x * PACK_EPB;
#pragma unroll
    for (int j = 0; j < 32; ++j) {
        int e = blockBase + j * 512 + t;         // coalesced per j
        bk[j] = -1;
        if (e < NEDGE_ALL) {
            int list = e >= NE;
            int ee = list ? e - NE : e;
            const int* ei = list ? ei_neg : ei_pos;
            int src = ei[ee];
            int dst = ei[NE + ee];
            int b = list * NBKT_PER + (dst >> 6);
            bk[j] = b;
            pk[j] = ((unsigned)(dst & 63) << 17) | (unsigned)src;
            atomicAdd(&cnt[b], 1);               // native int LDS atomic
        }
    }
    __syncthreads();

    // exclusive scan over cnt[3126]: 8-compress to 391, H-S, expand
    int s8[8];
    if (t < 391) {
        int acc = 0;
#pragma unroll
        for (int k = 0; k < 8; ++k) {
            int i = 8 * t + k;
            s8[k] = (i < NBKT) ? cnt[i] : 0;
            acc += s8[k];
        }
        ps[t] = acc;
    }
    __syncthreads();
    for (int d = 1; d < 391; d <<= 1) {
        int v = (t < 391 && t >= d) ? ps[t - d] : 0;
        __syncthreads();
        if (t < 391) ps[t] += v;
        __syncthreads();
    }
    const int r = blockIdx.x;
    if (t < 391) {
        int base = t ? ps[t - 1] : 0;
#pragma unroll
        for (int k = 0; k < 8; ++k) {
            int i = 8 * t + k;
            if (i < NBKT) {
                offTT[(long)i * OTT + r] = (unsigned short)base;
                cnt[i] = base;
                base += s8[k];
            }
        }
    }
    if (t == 390) offTT[(long)NBKT * OTT + r] = (unsigned short)(PACK_EPB < NEDGE_ALL - blockBase ? PACK_EPB : NEDGE_ALL - blockBase);
    __syncthreads();

    // compute all slots once (cursor atomics); bk[j] becomes the slot
#pragma unroll
    for (int j = 0; j < 32; ++j) {
        if (bk[j] >= 0)
            bk[j] = atomicAdd(&cnt[bk[j]], 1);
    }

    // ---- pass A: slots [0, 8192) ----
#pragma unroll
    for (int j = 0; j < 32; ++j) {
        if (bk[j] >= 0 && bk[j] < STG_HALF)
            stage[bk[j]] = pk[j];
    }
    __syncthreads();
    {
        const uint4* __restrict__ st4 = (const uint4*)stage;
        uint4* __restrict__ out4 = (uint4*)(plist + (long)blockIdx.x * PACK_EPB);
#pragma unroll
        for (int j = 0; j < 4; ++j)
            out4[j * 512 + t] = st4[j * 512 + t];
    }
    __syncthreads();

    // ---- pass B: slots [8192, 16384) ----
#pragma unroll
    for (int j = 0; j < 32; ++j) {
        if (bk[j] >= STG_HALF)
            stage[bk[j] - STG_HALF] = pk[j];
    }
    __syncthreads();
    {
        const uint4* __restrict__ st4 = (const uint4*)stage;
        uint4* __restrict__ out4 = (uint4*)(plist + (long)blockIdx.x * PACK_EPB + STG_HALF);
#pragma unroll
        for (int j = 0; j < 4; ++j)
            out4[j * 512 + t] = st4[j * 512 + t];
    }
}

// -------- phase 2: pos+neg gather + inline MLP epilogue (one block per 64 nodes) ---
// r20: grid 782 -> 1563 blocks (6.1/CU), LDS 28 -> ~18 KB (8 blocks/CU LDS cap).
// Same r8 machinery: runid table, int LDS atomics, hbuf accumulation across the
// two list passes, inline tanh+W2+softmax epilogue.
__global__ __launch_bounds__(256) void gather_fused_kernel(
    const __half* __restrict__ zbh,
    const __half* __restrict__ zch,
    const unsigned* __restrict__ plist,
    const unsigned short* __restrict__ offTT,   // [NBKT+2][OTT]
    const float* __restrict__ za,        // [NN*16]
    const float* __restrict__ W2,        // [16,48]
    const float* __restrict__ b2,        // [48]
    float* __restrict__ out)             // [NN*48]
{
    __shared__ unsigned srt[CAP2];       // 6 KB
    __shared__ int rb[NPB + 2];
    __shared__ int sc[NPB];
    __shared__ unsigned short rsL[NPB];
    __shared__ unsigned char runid[CAP2];// 1.5 KB slot -> run lookup
    __shared__ int nh[BKT_NODES];
    __shared__ int starts[BKT_NODES];
    __shared__ int ends[BKT_NODES];
    __shared__ int cur2[BKT_NODES];
    __shared__ float hbuf[BKT_NODES][17];// 4.4 KB pos+neg accumulator (pad 17)
    __shared__ float sW2[16 * 48];
    __shared__ float sb2[48];

    const int nb = blockIdx.x;           // 0..1562
    const int t = threadIdx.x;

    for (int i = t; i < 16 * 48; i += 256) sW2[i] = W2[i];
    if (t < 48) sb2[t] = b2[t];
    for (int i = t; i < BKT_NODES * 17; i += 256) ((float*)hbuf)[i] = 0.f;

    for (int list = 0; list < 2; ++list) {
        const int b = list * NBKT_PER + nb;
        __syncthreads();                 // previous phase fully drained

        if (t < NPB) {
            int s = offTT[(long)b * OTT + t];
            int e = offTT[(long)(b + 1) * OTT + t];
            rsL[t] = (unsigned short)s;
            sc[t] = e - s;
        }
        if (t < BKT_NODES) nh[t] = 0;
        __syncthreads();

        // inclusive H-S scan over 196 run lengths
        for (int d = 1; d < NPB; d <<= 1) {
            int v = (t < NPB && t >= d) ? sc[t - d] : 0;
            __syncthreads();
            if (t < NPB) sc[t] += v;
            __syncthreads();
        }
        if (t < NPB) rb[t + 1] = sc[t];
        if (t == 0) rb[0] = 0;
        __syncthreads();
        int cb = rb[NPB];
        if (cb > CAP2) cb = CAP2;

        // fill runid: slot i in [rb[r], rb[r+1]) belongs to run r
        if (t < NPB) {
            int s_ = min(rb[t], cb);
            int e_ = min(rb[t + 1], cb);
            for (int j = s_; j < e_; ++j) runid[j] = (unsigned char)t;
        }
        __syncthreads();

        unsigned held[KSTG];
#pragma unroll
        for (int k = 0; k < KSTG; ++k) {
            int i = t + k * 256;
            held[k] = 0;
            if (i < cb) {
                int lo = (int)runid[i];
                unsigned p = plist[(long)lo * PACK_EPB + rsL[lo] + (i - rb[lo])];
                held[k] = p;
                atomicAdd(&nh[p >> 17], 1);
            }
        }
        __syncthreads();

        for (int d = 1; d < BKT_NODES; d <<= 1) {
            int v = 0;
            if (t < BKT_NODES && t >= d) v = nh[t - d];
            __syncthreads();
            if (t < BKT_NODES) nh[t] += v;
            __syncthreads();
        }
        if (t < BKT_NODES) {
            int e_ = min(nh[t], CAP2);
            int s_ = t ? min(nh[t - 1], CAP2) : 0;
            starts[t] = s_;
            ends[t] = e_;
            cur2[t] = s_;
        }
        __syncthreads();

#pragma unroll
        for (int k = 0; k < KSTG; ++k) {
            int i = t + k * 256;
            if (i < cb) {
                unsigned p = held[k];
                int sl = atomicAdd(&cur2[p >> 17], 1);
                if (sl < CAP2) srt[sl] = p;
            }
        }
        __syncthreads();

        const int wave = t >> 6, lane = t & 63;
        const int g = lane >> 2;                 // 0..15 edge slot
        const int sub = lane & 3;                // 0..3 feature quad
        const half4v* __restrict__ z4 = (const half4v*)(list ? zch : zbh);

        for (int n = wave; n < BKT_NODES; n += 4) {
            int s = starts[n], e = ends[n];
            float a0 = 0.f, a1 = 0.f, a2 = 0.f, a3 = 0.f;
            for (int j = s; j < e; j += 16) {
                int i0 = j + g;
                int q = (i0 < e) ? (int)(srt[i0 < CAP2 ? i0 : 0] & 0x1FFFFu) : NN;
                half4v v = z4[q * 4 + sub];
                acc_pair(a0, a1, (half2v){v.x, v.y});
                acc_pair(a2, a3, (half2v){v.z, v.w});
            }
            a0 += __shfl_xor(a0, 4); a0 += __shfl_xor(a0, 8); a0 += __shfl_xor(a0, 16); a0 += __shfl_xor(a0, 32);
            a1 += __shfl_xor(a1, 4); a1 += __shfl_xor(a1, 8); a1 += __shfl_xor(a1, 16); a1 += __shfl_xor(a1, 32);
            a2 += __shfl_xor(a2, 4); a2 += __shfl_xor(a2, 8); a2 += __shfl_xor(a2, 16); a2 += __shfl_xor(a2, 32);
            a3 += __shfl_xor(a3, 4); a3 += __shfl_xor(a3, 8); a3 += __shfl_xor(a3, 16); a3 += __shfl_xor(a3, 32);
            if (g == 0) {
                // same wave owns node n in both list passes: += is race-free
                hbuf[n][4 * sub + 0] += a0;
                hbuf[n][4 * sub + 1] += a1;
                hbuf[n][4 * sub + 2] += a2;
                hbuf[n][4 * sub + 3] += a3;
            }
        }
    }
    __syncthreads();

    // ---- inline MLP epilogue: thread per node ----
    if (t < BKT_NODES) {
        const int gn = nb * BKT_NODES + t;
        if (gn < NN) {
            float h[16];
            const float4* A = (const float4*)(za + (long)gn * 16);
#pragma unroll
            for (int j4 = 0; j4 < 4; ++j4) {
                float4 a = A[j4];
                h[4 * j4 + 0] = tanhf(a.x + hbuf[t][4 * j4 + 0]);
                h[4 * j4 + 1] = tanhf(a.y + hbuf[t][4 * j4 + 1]);
                h[4 * j4 + 2] = tanhf(a.z + hbuf[t][4 * j4 + 2]);
                h[4 * j4 + 3] = tanhf(a.w + hbuf[t][4 * j4 + 3]);
            }

            float C[KF];
#pragma unroll
            for (int k = 0; k < KF; ++k) C[k] = sb2[k];
            for (int j = 0; j < 16; ++j) {
                const float hv = h[j];
                const float* w = &sW2[j * KF];
#pragma unroll
                for (int k = 0; k < KF; ++k) C[k] += hv * w[k];
            }

            float m = C[0];
#pragma unroll
            for (int k = 1; k < KF; ++k) m = fmaxf(m, C[k]);
            float ssum = 0.f;
#pragma unroll
            for (int k = 0; k < KF; ++k) { C[k] = expf(C[k] - m); ssum += C[k]; }
            const float inv = 1.0f / ssum;

            float4* po = (float4*)(out + (long)gn * KF);
#pragma unroll
            for (int k4 = 0; k4 < 12; ++k4)
                po[k4] = make_float4(C[4*k4] * inv, C[4*k4+1] * inv,
                                     C[4*k4+2] * inv, C[4*k4+3] * inv);
        }
    }
}

// ============== fallback path (if ws too small): unchanged ==============
__global__ __launch_bounds__(256) void scatter2_kernel(
    const float* __restrict__ x,
    const int* __restrict__ ei_pos,
    const int* __restrict__ ei_neg,
    float* acc_pos,
    float* acc_neg)
{
    const int list = blockIdx.y;
    const int* ei = list ? ei_neg : ei_pos;
    float* acc = list ? acc_neg : acc_pos;

    long t = (long)blockIdx.x * blockDim.x + threadIdx.x;
    const long total = (long)NE * 12;
    if (t >= total) return;

    int e = (int)(t / 12);
    int r = (int)(t - (long)e * 12);
    int k4 = r * 4;

    int src = ei[e];
    int dst = ei[NE + e];

    const float4 v = *(const float4*)(x + (long)src * KF + k4);
    float* p = acc + (long)dst * KF + k4;

    unsafeAtomicAdd(p + 0, v.x);
    unsafeAtomicAdd(p + 1, v.y);
    unsafeAtomicAdd(p + 2, v.z);
    unsafeAtomicAdd(p + 3, v.w);
}

// full MLP for the fallback path (xpos aliases out; reads own row before write)
__global__ __launch_bounds__(256) void mlp_softmax_kernel(
    const float* __restrict__ x,
    const float* xpos,
    const float* __restrict__ xneg,
    const float* __restrict__ W1,   // [144,16]
    const float* __restrict__ b1,
    const float* __restrict__ W2,   // [16,48]
    const float* __restrict__ b2,
    float* out)
{
    __shared__ float sW1[144 * 16];
    __shared__ float sW2[16 * 48];
    __shared__ float sb1[16];
    __shared__ float sb2[48];

    for (int i = threadIdx.x; i < 144 * 16; i += blockDim.x) sW1[i] = W1[i];
    for (int i = threadIdx.x; i < 16 * 48;  i += blockDim.x) sW2[i] = W2[i];
    if (threadIdx.x < 16) sb1[threadIdx.x] = b1[threadIdx.x];
    if (threadIdx.x < 48) sb2[threadIdx.x] = b2[threadIdx.x];
    __syncthreads();

    const int n = blockIdx.x * blockDim.x + threadIdx.x;
    if (n >= NN) return;

    float h[16];
#pragma unroll
    for (int j = 0; j < 16; ++j) h[j] = sb1[j];

    const float* srcs[3];
    srcs[0] = x    + (long)n * KF;
    srcs[1] = xpos + (long)n * KF;
    srcs[2] = xneg + (long)n * KF;

    for (int s = 0; s < 3; ++s) {
        const float* px = srcs[s];
        for (int i = 0; i < KF; ++i) {
            const float v = px[i];
            const float* w = &sW1[(s * KF + i) * 16];
#pragma unroll
            for (int j = 0; j < 16; ++j) h[j] += v * w[j];
        }
    }
#pragma unroll
    for (int j = 0; j < 16; ++j) h[j] = tanhf(h[j]);

    float C[KF];
#pragma unroll
    for (int k = 0; k < KF; ++k) C[k] = sb2[k];
    for (int j = 0; j < 16; ++j) {
        const float hv = h[j];
        const float* w = &sW2[j * KF];
#pragma unroll
        for (int k = 0; k < KF; ++k) C[k] += hv * w[k];
    }

    float m = C[0];
#pragma unroll
    for (int k = 1; k < KF; ++k) m = fmaxf(m, C[k]);
    float ssum = 0.f;
#pragma unroll
    for (int k = 0; k < KF; ++k) { C[k] = expf(C[k] - m); ssum += C[k]; }
    const float inv = 1.0f / ssum;

    float* po = out + (long)n * KF;
#pragma unroll
    for (int k = 0; k < KF; ++k) po[k] = C[k] * inv;
}

extern "C" void kernel_launch(void* const* d_in, const int* in_sizes, int n_in,
                              void* d_out, int out_size, void* d_ws, size_t ws_size,
                              hipStream_t stream)
{
    const float* x      = (const float*)d_in[0];
    const int*   ei_pos = (const int*)  d_in[1];
    const int*   ei_neg = (const int*)  d_in[2];
    const float* W1     = (const float*)d_in[3];
    const float* b1     = (const float*)d_in[4];
    const float* W2     = (const float*)d_in[5];
    const float* b2     = (const float*)d_in[6];

    float* out = (float*)d_out;

    const size_t za_bytes    = (size_t)NN * 16 * sizeof(float);               // 6.4 MB
    const size_t zh_bytes    = (size_t)(NN + 2) * 16 * sizeof(__half);        // 3.2 MB
    const size_t plist_bytes = (size_t)NPB * PACK_EPB * sizeof(unsigned);     // 12.85 MB
    const size_t offTT_bytes = (size_t)(NBKT + 2) * OTT * sizeof(unsigned short); // 1.25 MB

    // ws layout: [za | zbh | zch | plist | offTT]  (~27 MB)
    size_t off = 0;
    char* ws = (char*)d_ws;
    float*          za    = (float*)(ws + off);          off += za_bytes;
    __half*         zbh   = (__half*)(ws + off);         off += zh_bytes;
    __half*         zch   = (__half*)(ws + off);         off += zh_bytes;
    unsigned*       plist = (unsigned*)(ws + off);       off += plist_bytes;
    unsigned short* offTT = (unsigned short*)(ws + off); off += offTT_bytes;
    const size_t needed = off;

    if (ws_size >= needed) {
        pack_kernel<<<NPB, 512, 0, stream>>>(x, ei_pos, ei_neg, W1, b1, offTT, plist, za, zbh, zch);
        gather_fused_kernel<<<NBKT_PER, 256, 0, stream>>>(zbh, zch, plist, offTT, za, W2, b2, out);
    } else {
        // fallback: atomic scatter + full MLP (xpos aliases out)
        float* xpos = (float*)d_out;
        float* xneg = (float*)d_ws;      // needs 19.2 MB
        const size_t acc_bytes = (size_t)NN * KF * sizeof(float);
        hipMemsetAsync(xpos, 0, acc_bytes, stream);
        hipMemsetAsync(xneg, 0, acc_bytes, stream);
        const long total = (long)NE * 12;
        dim3 grid((unsigned)((total + 255) / 256), 2, 1);
        scatter2_kernel<<<grid, 256, 0, stream>>>(x, ei_pos, ei_neg, xpos, xneg);
        mlp_softmax_kernel<<<(NN + 255) / 256, 256, 0, stream>>>(x, xpos, xneg, W1, b1, W2, b2, out);
    }
}

// Round 10
// 222.315 us; speedup vs baseline: 1.0150x; 1.0150x over previous
//
#include <hip/hip_runtime.h>
#include <hip/hip_fp16.h>
#include <math.h>

#define NN 100000
#define NE 1600000
#define KF 48
#define NEDGE_ALL (2 * NE)

#define BKT_NODES 64                     // nodes per bucket (dst >> 6)
#define NBKT_PER  1563                   // ceil(100000/64)
#define NBKT      3126                   // pos buckets then neg buckets
#define PACK_EPB  16384                  // edges per pack block
#define STG_HALF  8192                   // LDS staging half-size (2 passes, 32 KB)
#define NPB       196                    // pack blocks = ceil(3.2M / 16384)
#define OTT       200                    // offTT row stride (>= NPB, even)
#define CAP2      1536                   // per-bucket srt capacity (mean 1024 + >8 sigma)
#define KSTG      6                      // staging registers per thread (6*256 >= CAP2)

typedef _Float16 half2v __attribute__((ext_vector_type(2)));
typedef _Float16 half4v __attribute__((ext_vector_type(4)));
typedef _Float16 half8v __attribute__((ext_vector_type(8)));

#if defined(__has_builtin)
#if __has_builtin(__builtin_amdgcn_fdot2)
#define HAVE_FDOT2 1
#endif
#endif

__device__ __forceinline__ void acc_pair(float& ax, float& ay, half2v v)
{
#ifdef HAVE_FDOT2
    ax = __builtin_amdgcn_fdot2(v, (half2v){(_Float16)1.f, (_Float16)0.f}, ax, false);
    ay = __builtin_amdgcn_fdot2(v, (half2v){(_Float16)0.f, (_Float16)1.f}, ay, false);
#else
    ax += (float)v.x;
    ay += (float)v.y;
#endif
}

// inclusive scan across the calling wave's 64 lanes (wave-synchronous, no barriers)
__device__ __forceinline__ int wave_incl_scan(int v)
{
    const int lane = threadIdx.x & 63;
#pragma unroll
    for (int d = 1; d < 64; d <<= 1) {
        int u = __shfl_up(v, d, 64);
        if (lane >= d) v += u;
    }
    return v;
}

// ------ phase 1: fused z-GEMM + LDS-sorted pack, writing offTT (transposed) --------
// r21: the 391-wide H-S scan (18 barriers) replaced by a single-wave shuffle
// scan (2 barriers). Everything else is the r9 structure.
__global__ __launch_bounds__(512) void pack_kernel(
    const float* __restrict__ x,
    const int* __restrict__ ei_pos,
    const int* __restrict__ ei_neg,
    const float* __restrict__ W1,        // [144,16] row-major
    const float* __restrict__ b1,        // [16]
    unsigned short* __restrict__ offTT,  // [NBKT+2][OTT]: offTT[b][r] = start of bucket b in block r
    unsigned* __restrict__ plist,        // [NPB * PACK_EPB]
    float* __restrict__ za,              // [NN*16] fp32 (x@W1a + b1)
    __half* __restrict__ zbh,            // [(NN+2)*16] fp16 (x@W1b) + zero sentinels
    __half* __restrict__ zch)            // [(NN+2)*16] fp16 (x@W1c) + zero sentinels
{
    __shared__ int cnt[NBKT];            // 12.5 KB hist -> becomes cursor
    __shared__ int ps[391];              // 1.6 KB 8-compressed scan
    __shared__ unsigned stage[STG_HALF]; // 32 KB sorted staging (half-block)
    __shared__ float sW1[144 * 16];      // 9.2 KB weights (broadcast reads)
    __shared__ float sb1[16];

    const int t = threadIdx.x;
    for (int i = t; i < 144 * 16; i += 512) sW1[i] = W1[i];
    if (t < 16) sb1[t] = b1[t];
    for (int i = t; i < NBKT; i += 512) cnt[i] = 0;
    __syncthreads();

    // --- fused z-GEMM: one thread per node, exact cover (196*512 = 100352) ---
    {
        const int n = blockIdx.x * 512 + t;
        if (n < NN + 2) {
            float aA[16], aB[16], aC[16];
#pragma unroll
            for (int j = 0; j < 16; ++j) { aA[j] = sb1[j]; aB[j] = 0.f; aC[j] = 0.f; }
            if (n < NN) {
                const float4* __restrict__ x4 = (const float4*)(x + (long)n * KF);
                for (int i4 = 0; i4 < 12; ++i4) {
                    float4 v = x4[i4];
                    float vv[4] = {v.x, v.y, v.z, v.w};
#pragma unroll
                    for (int c = 0; c < 4; ++c) {
                        const int f = i4 * 4 + c;
                        const float* wA = &sW1[f * 16];
                        const float* wB = &sW1[(48 + f) * 16];
                        const float* wC = &sW1[(96 + f) * 16];
                        const float s = vv[c];
#pragma unroll
                        for (int j = 0; j < 16; ++j) {
                            aA[j] += s * wA[j];
                            aB[j] += s * wB[j];
                            aC[j] += s * wC[j];
                        }
                    }
                }
                float4* za4 = (float4*)(za + (long)n * 16);
#pragma unroll
                for (int j4 = 0; j4 < 4; ++j4)
                    za4[j4] = make_float4(aA[4*j4], aA[4*j4+1], aA[4*j4+2], aA[4*j4+3]);
            }
            half8v hb0, hb1, hc0, hc1;
#pragma unroll
            for (int j = 0; j < 8; ++j) {
                hb0[j] = (_Float16)aB[j];     hb1[j] = (_Float16)aB[8 + j];
                hc0[j] = (_Float16)aC[j];     hc1[j] = (_Float16)aC[8 + j];
            }
            half8v* zb8 = (half8v*)zbh;
            half8v* zc8 = (half8v*)zch;
            zb8[(long)n * 2 + 0] = hb0;  zb8[(long)n * 2 + 1] = hb1;
            zc8[(long)n * 2 + 0] = hc0;  zc8[(long)n * 2 + 1] = hc1;
        }
    }

    unsigned pk[32];
    int bk[32];
    const int blockBase = blockIdx.x * PACK_EPB;
#pragma unroll
    for (int j = 0; j < 32; ++j) {
        int e = blockBase + j * 512 + t;         // coalesced per j
        bk[j] = -1;
        if (e < NEDGE_ALL) {
            int list = e >= NE;
            int ee = list ? e - NE : e;
            const int* ei = list ? ei_neg : ei_pos;
            int src = ei[ee];
            int dst = ei[NE + ee];
            int b = list * NBKT_PER + (dst >> 6);
            bk[j] = b;
            pk[j] = ((unsigned)(dst & 63) << 17) | (unsigned)src;
            atomicAdd(&cnt[b], 1);               // native int LDS atomic
        }
    }
    __syncthreads();

    // exclusive scan over cnt[3126]: 8-compress to ps[391], wave-scan, expand
    int s8[8];
    if (t < 391) {
        int acc = 0;
#pragma unroll
        for (int k = 0; k < 8; ++k) {
            int i = 8 * t + k;
            s8[k] = (i < NBKT) ? cnt[i] : 0;
            acc += s8[k];
        }
        ps[t] = acc;
    }
    __syncthreads();
    if (t < 64) {                        // wave 0: 7 elements per lane (448 >= 391)
        int base = 7 * t;
        int pre[7];
        int p = 0;
#pragma unroll
        for (int k = 0; k < 7; ++k) {
            int i = base + k;
            int v = (i < 391) ? ps[i] : 0;
            p += v;
            pre[k] = p;
        }
        int ex = wave_incl_scan(p) - p;
#pragma unroll
        for (int k = 0; k < 7; ++k) {
            int i = base + k;
            if (i < 391) ps[i] = ex + pre[k];    // inclusive scan result
        }
    }
    __syncthreads();
    const int r = blockIdx.x;
    if (t < 391) {
        int base = t ? ps[t - 1] : 0;
#pragma unroll
        for (int k = 0; k < 8; ++k) {
            int i = 8 * t + k;
            if (i < NBKT) {
                offTT[(long)i * OTT + r] = (unsigned short)base;
                cnt[i] = base;
                base += s8[k];
            }
        }
    }
    if (t == 390) {
        int tot = NEDGE_ALL - blockBase;
        if (tot > PACK_EPB) tot = PACK_EPB;
        offTT[(long)NBKT * OTT + r] = (unsigned short)tot;
    }
    __syncthreads();

    // compute all slots once (cursor atomics); bk[j] becomes the slot
#pragma unroll
    for (int j = 0; j < 32; ++j) {
        if (bk[j] >= 0)
            bk[j] = atomicAdd(&cnt[bk[j]], 1);
    }

    // ---- pass A: slots [0, 8192) ----
#pragma unroll
    for (int j = 0; j < 32; ++j) {
        if (bk[j] >= 0 && bk[j] < STG_HALF)
            stage[bk[j]] = pk[j];
    }
    __syncthreads();
    {
        const uint4* __restrict__ st4 = (const uint4*)stage;
        uint4* __restrict__ out4 = (uint4*)(plist + (long)blockIdx.x * PACK_EPB);
#pragma unroll
        for (int j = 0; j < 4; ++j)
            out4[j * 512 + t] = st4[j * 512 + t];
    }
    __syncthreads();

    // ---- pass B: slots [8192, 16384) ----
#pragma unroll
    for (int j = 0; j < 32; ++j) {
        if (bk[j] >= STG_HALF)
            stage[bk[j] - STG_HALF] = pk[j];
    }
    __syncthreads();
    {
        const uint4* __restrict__ st4 = (const uint4*)stage;
        uint4* __restrict__ out4 = (uint4*)(plist + (long)blockIdx.x * PACK_EPB + STG_HALF);
#pragma unroll
        for (int j = 0; j < 4; ++j)
            out4[j * 512 + t] = st4[j * 512 + t];
    }
}

// -------- phase 2: pos+neg gather + inline MLP epilogue (one block per 64 nodes) ---
// r21: both block-wide H-S scans replaced by wave-0 shuffle scans. Barriers per
// list pass: ~28 -> 7. BKT_NODES=64 == wave width, so the node-histogram scan
// is a single wave_incl_scan. All data flow identical to r9 (proven correct).
__global__ __launch_bounds__(256) void gather_fused_kernel(
    const __half* __restrict__ zbh,
    const __half* __restrict__ zch,
    const unsigned* __restrict__ plist,
    const unsigned short* __restrict__ offTT,   // [NBKT+2][OTT]
    const float* __restrict__ za,        // [NN*16]
    const float* __restrict__ W2,        // [16,48]
    const float* __restrict__ b2,        // [48]
    float* __restrict__ out)             // [NN*48]
{
    __shared__ unsigned srt[CAP2];       // 6 KB
    __shared__ int rb[NPB + 2];
    __shared__ int sc[NPB];
    __shared__ unsigned short rsL[NPB];
    __shared__ unsigned char runid[CAP2];// 1.5 KB slot -> run lookup
    __shared__ int nh[BKT_NODES];
    __shared__ int starts[BKT_NODES];
    __shared__ int ends[BKT_NODES];
    __shared__ int cur2[BKT_NODES];
    __shared__ float hbuf[BKT_NODES][17];// 4.4 KB pos+neg accumulator (pad 17)
    __shared__ float sW2[16 * 48];
    __shared__ float sb2[48];

    const int nb = blockIdx.x;           // 0..1562
    const int t = threadIdx.x;

    for (int i = t; i < 16 * 48; i += 256) sW2[i] = W2[i];
    if (t < 48) sb2[t] = b2[t];
    for (int i = t; i < BKT_NODES * 17; i += 256) ((float*)hbuf)[i] = 0.f;

    for (int list = 0; list < 2; ++list) {
        const int b = list * NBKT_PER + nb;
        __syncthreads();                 // previous phase fully drained

        if (t < NPB) {
            int s = offTT[(long)b * OTT + t];
            int e = offTT[(long)(b + 1) * OTT + t];
            rsL[t] = (unsigned short)s;
            sc[t] = e - s;
        }
        if (t < BKT_NODES) nh[t] = 0;
        __syncthreads();

        // wave-0 shuffle scan of the 196 run lengths -> rb[] exclusive
        if (t < 64) {
            int base = 4 * t;
            int v0 = (base     < NPB) ? sc[base]     : 0;
            int v1 = (base + 1 < NPB) ? sc[base + 1] : 0;
            int v2 = (base + 2 < NPB) ? sc[base + 2] : 0;
            int v3 = (base + 3 < NPB) ? sc[base + 3] : 0;
            int p0 = v0, p1 = p0 + v1, p2 = p1 + v2, p3 = p2 + v3;
            int ex = wave_incl_scan(p3) - p3;
            if (base     <= NPB) rb[base]     = ex;
            if (base + 1 <= NPB) rb[base + 1] = ex + p0;
            if (base + 2 <= NPB) rb[base + 2] = ex + p1;
            if (base + 3 <= NPB) rb[base + 3] = ex + p2;
            if (base + 4 <= NPB) rb[base + 4] = ex + p3;
        }
        __syncthreads();
        int cb = rb[NPB];
        if (cb > CAP2) cb = CAP2;

        // fill runid: slot i in [rb[r], rb[r+1]) belongs to run r
        if (t < NPB) {
            int s_ = min(rb[t], cb);
            int e_ = min(rb[t + 1], cb);
            for (int j = s_; j < e_; ++j) runid[j] = (unsigned char)t;
        }
        __syncthreads();

        unsigned held[KSTG];
#pragma unroll
        for (int k = 0; k < KSTG; ++k) {
            int i = t + k * 256;
            held[k] = 0;
            if (i < cb) {
                int lo = (int)runid[i];
                unsigned p = plist[(long)lo * PACK_EPB + rsL[lo] + (i - rb[lo])];
                held[k] = p;
                atomicAdd(&nh[p >> 17], 1);
            }
        }
        __syncthreads();

        // wave-0 shuffle scan of the 64-node histogram -> starts/ends/cur2
        if (t < 64) {
            int v = nh[t];
            int inc = wave_incl_scan(v);
            int e_ = min(inc, CAP2);
            int s_ = min(inc - v, CAP2);
            starts[t] = s_;
            ends[t] = e_;
            cur2[t] = s_;
        }
        __syncthreads();

#pragma unroll
        for (int k = 0; k < KSTG; ++k) {
            int i = t + k * 256;
            if (i < cb) {
                unsigned p = held[k];
                int sl = atomicAdd(&cur2[p >> 17], 1);
                if (sl < CAP2) srt[sl] = p;
            }
        }
        __syncthreads();

        const int wave = t >> 6, lane = t & 63;
        const int g = lane >> 2;                 // 0..15 edge slot
        const int sub = lane & 3;                // 0..3 feature quad
        const half4v* __restrict__ z4 = (const half4v*)(list ? zch : zbh);

        for (int n = wave; n < BKT_NODES; n += 4) {
            int s = starts[n], e = ends[n];
            float a0 = 0.f, a1 = 0.f, a2 = 0.f, a3 = 0.f;
            for (int j = s; j < e; j += 16) {
                int i0 = j + g;
                int q = (i0 < e) ? (int)(srt[i0 < CAP2 ? i0 : 0] & 0x1FFFFu) : NN;
                half4v v = z4[q * 4 + sub];
                acc_pair(a0, a1, (half2v){v.x, v.y});
                acc_pair(a2, a3, (half2v){v.z, v.w});
            }
            a0 += __shfl_xor(a0, 4); a0 += __shfl_xor(a0, 8); a0 += __shfl_xor(a0, 16); a0 += __shfl_xor(a0, 32);
            a1 += __shfl_xor(a1, 4); a1 += __shfl_xor(a1, 8); a1 += __shfl_xor(a1, 16); a1 += __shfl_xor(a1, 32);
            a2 += __shfl_xor(a2, 4); a2 += __shfl_xor(a2, 8); a2 += __shfl_xor(a2, 16); a2 += __shfl_xor(a2, 32);
            a3 += __shfl_xor(a3, 4); a3 += __shfl_xor(a3, 8); a3 += __shfl_xor(a3, 16); a3 += __shfl_xor(a3, 32);
            if (g == 0) {
                // same wave owns node n in both list passes: += is race-free
                hbuf[n][4 * sub + 0] += a0;
                hbuf[n][4 * sub + 1] += a1;
                hbuf[n][4 * sub + 2] += a2;
                hbuf[n][4 * sub + 3] += a3;
            }
        }
    }
    __syncthreads();

    // ---- inline MLP epilogue: thread per node ----
    if (t < BKT_NODES) {
        const int gn = nb * BKT_NODES + t;
        if (gn < NN) {
            float h[16];
            const float4* A = (const float4*)(za + (long)gn * 16);
#pragma unroll
            for (int j4 = 0; j4 < 4; ++j4) {
                float4 a = A[j4];
                h[4 * j4 + 0] = tanhf(a.x + hbuf[t][4 * j4 + 0]);
                h[4 * j4 + 1] = tanhf(a.y + hbuf[t][4 * j4 + 1]);
                h[4 * j4 + 2] = tanhf(a.z + hbuf[t][4 * j4 + 2]);
                h[4 * j4 + 3] = tanhf(a.w + hbuf[t][4 * j4 + 3]);
            }

            float C[KF];
#pragma unroll
            for (int k = 0; k < KF; ++k) C[k] = sb2[k];
            for (int j = 0; j < 16; ++j) {
                const float hv = h[j];
                const float* w = &sW2[j * KF];
#pragma unroll
                for (int k = 0; k < KF; ++k) C[k] += hv * w[k];
            }

            float m = C[0];
#pragma unroll
            for (int k = 1; k < KF; ++k) m = fmaxf(m, C[k]);
            float ssum = 0.f;
#pragma unroll
            for (int k = 0; k < KF; ++k) { C[k] = expf(C[k] - m); ssum += C[k]; }
            const float inv = 1.0f / ssum;

            float4* po = (float4*)(out + (long)gn * KF);
#pragma unroll
            for (int k4 = 0; k4 < 12; ++k4)
                po[k4] = make_float4(C[4*k4] * inv, C[4*k4+1] * inv,
                                     C[4*k4+2] * inv, C[4*k4+3] * inv);
        }
    }
}

// ============== fallback path (if ws too small): unchanged ==============
__global__ __launch_bounds__(256) void scatter2_kernel(
    const float* __restrict__ x,
    const int* __restrict__ ei_pos,
    const int* __restrict__ ei_neg,
    float* acc_pos,
    float* acc_neg)
{
    const int list = blockIdx.y;
    const int* ei = list ? ei_neg : ei_pos;
    float* acc = list ? acc_neg : acc_pos;

    long t = (long)blockIdx.x * blockDim.x + threadIdx.x;
    const long total = (long)NE * 12;
    if (t >= total) return;

    int e = (int)(t / 12);
    int r = (int)(t - (long)e * 12);
    int k4 = r * 4;

    int src = ei[e];
    int dst = ei[NE + e];

    const float4 v = *(const float4*)(x + (long)src * KF + k4);
    float* p = acc + (long)dst * KF + k4;

    unsafeAtomicAdd(p + 0, v.x);
    unsafeAtomicAdd(p + 1, v.y);
    unsafeAtomicAdd(p + 2, v.z);
    unsafeAtomicAdd(p + 3, v.w);
}

// full MLP for the fallback path (xpos aliases out; reads own row before write)
__global__ __launch_bounds__(256) void mlp_softmax_kernel(
    const float* __restrict__ x,
    const float* xpos,
    const float* __restrict__ xneg,
    const float* __restrict__ W1,   // [144,16]
    const float* __restrict__ b1,
    const float* __restrict__ W2,   // [16,48]
    const float* __restrict__ b2,
    float* out)
{
    __shared__ float sW1[144 * 16];
    __shared__ float sW2[16 * 48];
    __shared__ float sb1[16];
    __shared__ float sb2[48];

    for (int i = threadIdx.x; i < 144 * 16; i += blockDim.x) sW1[i] = W1[i];
    for (int i = threadIdx.x; i < 16 * 48;  i += blockDim.x) sW2[i] = W2[i];
    if (threadIdx.x < 16) sb1[threadIdx.x] = b1[threadIdx.x];
    if (threadIdx.x < 48) sb2[threadIdx.x] = b2[threadIdx.x];
    __syncthreads();

    const int n = blockIdx.x * blockDim.x + threadIdx.x;
    if (n >= NN) return;

    float h[16];
#pragma unroll
    for (int j = 0; j < 16; ++j) h[j] = sb1[j];

    const float* srcs[3];
    srcs[0] = x    + (long)n * KF;
    srcs[1] = xpos + (long)n * KF;
    srcs[2] = xneg + (long)n * KF;

    for (int s = 0; s < 3; ++s) {
        const float* px = srcs[s];
        for (int i = 0; i < KF; ++i) {
            const float v = px[i];
            const float* w = &sW1[(s * KF + i) * 16];
#pragma unroll
            for (int j = 0; j < 16; ++j) h[j] += v * w[j];
        }
    }
#pragma unroll
    for (int j = 0; j < 16; ++j) h[j] = tanhf(h[j]);

    float C[KF];
#pragma unroll
    for (int k = 0; k < KF; ++k) C[k] = sb2[k];
    for (int j = 0; j < 16; ++j) {
        const float hv = h[j];
        const float* w = &sW2[j * KF];
#pragma unroll
        for (int k = 0; k < KF; ++k) C[k] += hv * w[k];
    }

    float m = C[0];
#pragma unroll
    for (int k = 1; k < KF; ++k) m = fmaxf(m, C[k]);
    float ssum = 0.f;
#pragma unroll
    for (int k = 0; k < KF; ++k) { C[k] = expf(C[k] - m); ssum += C[k]; }
    const float inv = 1.0f / ssum;

    float* po = out + (long)n * KF;
#pragma unroll
    for (int k = 0; k < KF; ++k) po[k] = C[k] * inv;
}

extern "C" void kernel_launch(void* const* d_in, const int* in_sizes, int n_in,
                              void* d_out, int out_size, void* d_ws, size_t ws_size,
                              hipStream_t stream)
{
    const float* x      = (const float*)d_in[0];
    const int*   ei_pos = (const int*)  d_in[1];
    const int*   ei_neg = (const int*)  d_in[2];
    const float* W1     = (const float*)d_in[3];
    const float* b1     = (const float*)d_in[4];
    const float* W2     = (const float*)d_in[5];
    const float* b2     = (const float*)d_in[6];

    float* out = (float*)d_out;

    const size_t za_bytes    = (size_t)NN * 16 * sizeof(float);               // 6.4 MB
    const size_t zh_bytes    = (size_t)(NN + 2) * 16 * sizeof(__half);        // 3.2 MB
    const size_t plist_bytes = (size_t)NPB * PACK_EPB * sizeof(unsigned);     // 12.85 MB
    const size_t offTT_bytes = (size_t)(NBKT + 2) * OTT * sizeof(unsigned short); // 1.25 MB

    // ws layout: [za | zbh | zch | plist | offTT]  (~27 MB)
    size_t off = 0;
    char* ws = (char*)d_ws;
    float*          za    = (float*)(ws + off);          off += za_bytes;
    __half*         zbh   = (__half*)(ws + off);         off += zh_bytes;
    __half*         zch   = (__half*)(ws + off);         off += zh_bytes;
    unsigned*       plist = (unsigned*)(ws + off);       off += plist_bytes;
    unsigned short* offTT = (unsigned short*)(ws + off); off += offTT_bytes;
    const size_t needed = off;

    if (ws_size >= needed) {
        pack_kernel<<<NPB, 512, 0, stream>>>(x, ei_pos, ei_neg, W1, b1, offTT, plist, za, zbh, zch);
        gather_fused_kernel<<<NBKT_PER, 256, 0, stream>>>(zbh, zch, plist, offTT, za, W2, b2, out);
    } else {
        // fallback: atomic scatter + full MLP (xpos aliases out)
        float* xpos = (float*)d_out;
        float* xneg = (float*)d_ws;      // needs 19.2 MB
        const size_t acc_bytes = (size_t)NN * KF * sizeof(float);
        hipMemsetAsync(xpos, 0, acc_bytes, stream);
        hipMemsetAsync(xneg, 0, acc_bytes, stream);
        const long total = (long)NE * 12;
        dim3 grid((unsigned)((total + 255) / 256), 2, 1);
        scatter2_kernel<<<grid, 256, 0, stream>>>(x, ei_pos, ei_neg, xpos, xneg);
        mlp_softmax_kernel<<<(NN + 255) / 256, 256, 0, stream>>>(x, xpos, xneg, W1, b1, W2, b2, out);
    }
}

// Round 11
// 217.287 us; speedup vs baseline: 1.0385x; 1.0231x over previous
//
#include <hip/hip_runtime.h>
#include <hip/hip_fp16.h>
#include <math.h>

#define NN 100000
#define NE 1600000
#define KF 48
#define NEDGE_ALL (2 * NE)

#define BKT_NODES 64                     // nodes per bucket (dst >> 6)
#define NBKT_PER  1563                   // ceil(100000/64)
#define NBKT      3126                   // pos buckets then neg buckets
#define PACK_EPB  16384                  // edges per pack block
#define STG_HALF  8192                   // LDS staging half-size (2 passes, 32 KB)
#define NPB       196                    // pack blocks = ceil(3.2M / 16384)
#define OTT       200                    // offTT row stride (>= NPB, even)
#define CAP2      1536                   // per-bucket srt capacity (mean 1024 + >8 sigma)
#define KSTG      6                      // staging registers per thread (6*256 >= CAP2)

typedef _Float16 half2v __attribute__((ext_vector_type(2)));
typedef _Float16 half4v __attribute__((ext_vector_type(4)));
typedef _Float16 half8v __attribute__((ext_vector_type(8)));

#if defined(__has_builtin)
#if __has_builtin(__builtin_amdgcn_fdot2)
#define HAVE_FDOT2 1
#endif
#endif

__device__ __forceinline__ void acc_pair(float& ax, float& ay, half2v v)
{
#ifdef HAVE_FDOT2
    ax = __builtin_amdgcn_fdot2(v, (half2v){(_Float16)1.f, (_Float16)0.f}, ax, false);
    ay = __builtin_amdgcn_fdot2(v, (half2v){(_Float16)0.f, (_Float16)1.f}, ay, false);
#else
    ax += (float)v.x;
    ay += (float)v.y;
#endif
}

// inclusive scan across the calling wave's 64 lanes (wave-synchronous, no barriers)
__device__ __forceinline__ int wave_incl_scan(int v)
{
    const int lane = threadIdx.x & 63;
#pragma unroll
    for (int d = 1; d < 64; d <<= 1) {
        int u = __shfl_up(v, d, 64);
        if (lane >= d) v += u;
    }
    return v;
}

// ------ phase 1: fused z-GEMM + LDS-sorted pack, writing offTT (transposed) --------
// (unchanged from r10: wave-scan, 16K granule, two-pass staging, direct offTT)
__global__ __launch_bounds__(512) void pack_kernel(
    const float* __restrict__ x,
    const int* __restrict__ ei_pos,
    const int* __restrict__ ei_neg,
    const float* __restrict__ W1,        // [144,16] row-major
    const float* __restrict__ b1,        // [16]
    unsigned short* __restrict__ offTT,  // [NBKT+2][OTT]
    unsigned* __restrict__ plist,        // [NPB * PACK_EPB]
    float* __restrict__ za,              // [NN*16] fp32 (x@W1a + b1)
    __half* __restrict__ zbh,            // [(NN+2)*16] fp16 (x@W1b) + zero sentinels
    __half* __restrict__ zch)            // [(NN+2)*16] fp16 (x@W1c) + zero sentinels
{
    __shared__ int cnt[NBKT];            // 12.5 KB hist -> becomes cursor
    __shared__ int ps[391];              // 1.6 KB 8-compressed scan
    __shared__ unsigned stage[STG_HALF]; // 32 KB sorted staging (half-block)
    __shared__ float sW1[144 * 16];      // 9.2 KB weights (broadcast reads)
    __shared__ float sb1[16];

    const int t = threadIdx.x;
    for (int i = t; i < 144 * 16; i += 512) sW1[i] = W1[i];
    if (t < 16) sb1[t] = b1[t];
    for (int i = t; i < NBKT; i += 512) cnt[i] = 0;
    __syncthreads();

    // --- fused z-GEMM: one thread per node, exact cover (196*512 = 100352) ---
    {
        const int n = blockIdx.x * 512 + t;
        if (n < NN + 2) {
            float aA[16], aB[16], aC[16];
#pragma unroll
            for (int j = 0; j < 16; ++j) { aA[j] = sb1[j]; aB[j] = 0.f; aC[j] = 0.f; }
            if (n < NN) {
                const float4* __restrict__ x4 = (const float4*)(x + (long)n * KF);
                for (int i4 = 0; i4 < 12; ++i4) {
                    float4 v = x4[i4];
                    float vv[4] = {v.x, v.y, v.z, v.w};
#pragma unroll
                    for (int c = 0; c < 4; ++c) {
                        const int f = i4 * 4 + c;
                        const float* wA = &sW1[f * 16];
                        const float* wB = &sW1[(48 + f) * 16];
                        const float* wC = &sW1[(96 + f) * 16];
                        const float s = vv[c];
#pragma unroll
                        for (int j = 0; j < 16; ++j) {
                            aA[j] += s * wA[j];
                            aB[j] += s * wB[j];
                            aC[j] += s * wC[j];
                        }
                    }
                }
                float4* za4 = (float4*)(za + (long)n * 16);
#pragma unroll
                for (int j4 = 0; j4 < 4; ++j4)
                    za4[j4] = make_float4(aA[4*j4], aA[4*j4+1], aA[4*j4+2], aA[4*j4+3]);
            }
            half8v hb0, hb1, hc0, hc1;
#pragma unroll
            for (int j = 0; j < 8; ++j) {
                hb0[j] = (_Float16)aB[j];     hb1[j] = (_Float16)aB[8 + j];
                hc0[j] = (_Float16)aC[j];     hc1[j] = (_Float16)aC[8 + j];
            }
            half8v* zb8 = (half8v*)zbh;
            half8v* zc8 = (half8v*)zch;
            zb8[(long)n * 2 + 0] = hb0;  zb8[(long)n * 2 + 1] = hb1;
            zc8[(long)n * 2 + 0] = hc0;  zc8[(long)n * 2 + 1] = hc1;
        }
    }

    unsigned pk[32];
    int bk[32];
    const int blockBase = blockIdx.x * PACK_EPB;
#pragma unroll
    for (int j = 0; j < 32; ++j) {
        int e = blockBase + j * 512 + t;         // coalesced per j
        bk[j] = -1;
        if (e < NEDGE_ALL) {
            int list = e >= NE;
            int ee = list ? e - NE : e;
            const int* ei = list ? ei_neg : ei_pos;
            int src = ei[ee];
            int dst = ei[NE + ee];
            int b = list * NBKT_PER + (dst >> 6);
            bk[j] = b;
            pk[j] = ((unsigned)(dst & 63) << 17) | (unsigned)src;
            atomicAdd(&cnt[b], 1);               // native int LDS atomic
        }
    }
    __syncthreads();

    // exclusive scan over cnt[3126]: 8-compress to ps[391], wave-scan, expand
    int s8[8];
    if (t < 391) {
        int acc = 0;
#pragma unroll
        for (int k = 0; k < 8; ++k) {
            int i = 8 * t + k;
            s8[k] = (i < NBKT) ? cnt[i] : 0;
            acc += s8[k];
        }
        ps[t] = acc;
    }
    __syncthreads();
    if (t < 64) {                        // wave 0: 7 elements per lane (448 >= 391)
        int base = 7 * t;
        int pre[7];
        int p = 0;
#pragma unroll
        for (int k = 0; k < 7; ++k) {
            int i = base + k;
            int v = (i < 391) ? ps[i] : 0;
            p += v;
            pre[k] = p;
        }
        int ex = wave_incl_scan(p) - p;
#pragma unroll
        for (int k = 0; k < 7; ++k) {
            int i = base + k;
            if (i < 391) ps[i] = ex + pre[k];    // inclusive scan result
        }
    }
    __syncthreads();
    const int r = blockIdx.x;
    if (t < 391) {
        int base = t ? ps[t - 1] : 0;
#pragma unroll
        for (int k = 0; k < 8; ++k) {
            int i = 8 * t + k;
            if (i < NBKT) {
                offTT[(long)i * OTT + r] = (unsigned short)base;
                cnt[i] = base;
                base += s8[k];
            }
        }
    }
    if (t == 390) {
        int tot = NEDGE_ALL - blockBase;
        if (tot > PACK_EPB) tot = PACK_EPB;
        offTT[(long)NBKT * OTT + r] = (unsigned short)tot;
    }
    __syncthreads();

    // compute all slots once (cursor atomics); bk[j] becomes the slot
#pragma unroll
    for (int j = 0; j < 32; ++j) {
        if (bk[j] >= 0)
            bk[j] = atomicAdd(&cnt[bk[j]], 1);
    }

    // ---- pass A: slots [0, 8192) ----
#pragma unroll
    for (int j = 0; j < 32; ++j) {
        if (bk[j] >= 0 && bk[j] < STG_HALF)
            stage[bk[j]] = pk[j];
    }
    __syncthreads();
    {
        const uint4* __restrict__ st4 = (const uint4*)stage;
        uint4* __restrict__ out4 = (uint4*)(plist + (long)blockIdx.x * PACK_EPB);
#pragma unroll
        for (int j = 0; j < 4; ++j)
            out4[j * 512 + t] = st4[j * 512 + t];
    }
    __syncthreads();

    // ---- pass B: slots [8192, 16384) ----
#pragma unroll
    for (int j = 0; j < 32; ++j) {
        if (bk[j] >= STG_HALF)
            stage[bk[j] - STG_HALF] = pk[j];
    }
    __syncthreads();
    {
        const uint4* __restrict__ st4 = (const uint4*)stage;
        uint4* __restrict__ out4 = (uint4*)(plist + (long)blockIdx.x * PACK_EPB + STG_HALF);
#pragma unroll
        for (int j = 0; j < 4; ++j)
            out4[j * 512 + t] = st4[j * 512 + t];
    }
}

// -------- phase 2: pos+neg gather + inline MLP epilogue (one block per 64 nodes) ---
// r22 changes (target: memory-latency stall at low occupancy, per r10 counters):
//  (a) LDS 18.4 -> ~14.3 KB via dead-phase overlays (sc lives in srt; sW2/sb2
//      loaded into srt/rb AFTER the payload, both dead by the epilogue) ->
//      4 blocks per 64 KB occupancy window instead of 3.
//  (b) node loop unrolled x2 (nodes n and n+4): two independent
//      srt-read -> z-load -> fdot2 chains in flight per wave.
__global__ __launch_bounds__(256) void gather_fused_kernel(
    const __half* __restrict__ zbh,
    const __half* __restrict__ zch,
    const unsigned* __restrict__ plist,
    const unsigned short* __restrict__ offTT,   // [NBKT+2][OTT]
    const float* __restrict__ za,        // [NN*16]
    const float* __restrict__ W2,        // [16,48]
    const float* __restrict__ b2,        // [48]
    float* __restrict__ out)             // [NN*48]
{
    __shared__ unsigned srt[CAP2];       // 6 KB (also hosts sc scratch, then sW2)
    __shared__ int rb[NPB + 2];          // 792 B (hosts sb2 in epilogue)
    __shared__ unsigned short rsL[NPB];  // 392 B
    __shared__ unsigned char runid[CAP2];// 1.5 KB slot -> run lookup
    __shared__ int nh[BKT_NODES];
    __shared__ int starts[BKT_NODES];
    __shared__ int ends[BKT_NODES];
    __shared__ int cur2[BKT_NODES];
    __shared__ float hbuf[BKT_NODES][17];// 4.4 KB pos+neg accumulator (pad 17)

    const int nb = blockIdx.x;           // 0..1562
    const int t = threadIdx.x;

    for (int i = t; i < BKT_NODES * 17; i += 256) ((float*)hbuf)[i] = 0.f;

    for (int list = 0; list < 2; ++list) {
        const int b = list * NBKT_PER + nb;
        __syncthreads();                 // previous phase fully drained

        int* sc = (int*)srt;             // overlay: srt not live until sort-scatter
        if (t < NPB) {
            int s = offTT[(long)b * OTT + t];
            int e = offTT[(long)(b + 1) * OTT + t];
            rsL[t] = (unsigned short)s;
            sc[t] = e - s;
        }
        if (t < BKT_NODES) nh[t] = 0;
        __syncthreads();

        // wave-0 shuffle scan of the 196 run lengths -> rb[] exclusive
        if (t < 64) {
            int base = 4 * t;
            int v0 = (base     < NPB) ? sc[base]     : 0;
            int v1 = (base + 1 < NPB) ? sc[base + 1] : 0;
            int v2 = (base + 2 < NPB) ? sc[base + 2] : 0;
            int v3 = (base + 3 < NPB) ? sc[base + 3] : 0;
            int p0 = v0, p1 = p0 + v1, p2 = p1 + v2, p3 = p2 + v3;
            int ex = wave_incl_scan(p3) - p3;
            if (base     <= NPB) rb[base]     = ex;
            if (base + 1 <= NPB) rb[base + 1] = ex + p0;
            if (base + 2 <= NPB) rb[base + 2] = ex + p1;
            if (base + 3 <= NPB) rb[base + 3] = ex + p2;
            if (base + 4 <= NPB) rb[base + 4] = ex + p3;
        }
        __syncthreads();
        int cb = rb[NPB];
        if (cb > CAP2) cb = CAP2;

        // fill runid: slot i in [rb[r], rb[r+1]) belongs to run r
        if (t < NPB) {
            int s_ = min(rb[t], cb);
            int e_ = min(rb[t + 1], cb);
            for (int j = s_; j < e_; ++j) runid[j] = (unsigned char)t;
        }
        __syncthreads();

        unsigned held[KSTG];
#pragma unroll
        for (int k = 0; k < KSTG; ++k) {
            int i = t + k * 256;
            held[k] = 0;
            if (i < cb) {
                int lo = (int)runid[i];
                unsigned p = plist[(long)lo * PACK_EPB + rsL[lo] + (i - rb[lo])];
                held[k] = p;
                atomicAdd(&nh[p >> 17], 1);
            }
        }
        __syncthreads();

        // wave-0 shuffle scan of the 64-node histogram -> starts/ends/cur2
        if (t < 64) {
            int v = nh[t];
            int inc = wave_incl_scan(v);
            int e_ = min(inc, CAP2);
            int s_ = min(inc - v, CAP2);
            starts[t] = s_;
            ends[t] = e_;
            cur2[t] = s_;
        }
        __syncthreads();

#pragma unroll
        for (int k = 0; k < KSTG; ++k) {
            int i = t + k * 256;
            if (i < cb) {
                unsigned p = held[k];
                int sl = atomicAdd(&cur2[p >> 17], 1);
                if (sl < CAP2) srt[sl] = p;
            }
        }
        __syncthreads();

        const int wave = t >> 6, lane = t & 63;
        const int g = lane >> 2;                 // 0..15 edge slot
        const int sub = lane & 3;                // 0..3 feature quad
        const half4v* __restrict__ z4 = (const half4v*)(list ? zch : zbh);

        // node loop unrolled x2: nodes n and n+4 interleaved for 2x loads in flight
        for (int n = wave; n < BKT_NODES; n += 8) {
            const int nA = n, nB = n + 4;
            int sA = starts[nA], eA = ends[nA];
            int sB = starts[nB], eB = ends[nB];
            float a0 = 0.f, a1 = 0.f, a2 = 0.f, a3 = 0.f;
            float c0 = 0.f, c1 = 0.f, c2 = 0.f, c3 = 0.f;
            int jA = sA, jB = sB;
            while (jA < eA || jB < eB) {
                int iA = jA + g, iB = jB + g;
                int qA = (iA < eA) ? (int)(srt[iA < CAP2 ? iA : 0] & 0x1FFFFu) : NN;
                int qB = (iB < eB) ? (int)(srt[iB < CAP2 ? iB : 0] & 0x1FFFFu) : NN;
                half4v vA = z4[(long)qA * 4 + sub];
                half4v vB = z4[(long)qB * 4 + sub];
                acc_pair(a0, a1, (half2v){vA.x, vA.y});
                acc_pair(a2, a3, (half2v){vA.z, vA.w});
                acc_pair(c0, c1, (half2v){vB.x, vB.y});
                acc_pair(c2, c3, (half2v){vB.z, vB.w});
                jA += 16; jB += 16;
            }
            a0 += __shfl_xor(a0, 4); a0 += __shfl_xor(a0, 8); a0 += __shfl_xor(a0, 16); a0 += __shfl_xor(a0, 32);
            a1 += __shfl_xor(a1, 4); a1 += __shfl_xor(a1, 8); a1 += __shfl_xor(a1, 16); a1 += __shfl_xor(a1, 32);
            a2 += __shfl_xor(a2, 4); a2 += __shfl_xor(a2, 8); a2 += __shfl_xor(a2, 16); a2 += __shfl_xor(a2, 32);
            a3 += __shfl_xor(a3, 4); a3 += __shfl_xor(a3, 8); a3 += __shfl_xor(a3, 16); a3 += __shfl_xor(a3, 32);
            c0 += __shfl_xor(c0, 4); c0 += __shfl_xor(c0, 8); c0 += __shfl_xor(c0, 16); c0 += __shfl_xor(c0, 32);
            c1 += __shfl_xor(c1, 4); c1 += __shfl_xor(c1, 8); c1 += __shfl_xor(c1, 16); c1 += __shfl_xor(c1, 32);
            c2 += __shfl_xor(c2, 4); c2 += __shfl_xor(c2, 8); c2 += __shfl_xor(c2, 16); c2 += __shfl_xor(c2, 32);
            c3 += __shfl_xor(c3, 4); c3 += __shfl_xor(c3, 8); c3 += __shfl_xor(c3, 16); c3 += __shfl_xor(c3, 32);
            if (g == 0) {
                // same wave owns these nodes in both list passes: += race-free
                hbuf[nA][4 * sub + 0] += a0;
                hbuf[nA][4 * sub + 1] += a1;
                hbuf[nA][4 * sub + 2] += a2;
                hbuf[nA][4 * sub + 3] += a3;
                hbuf[nB][4 * sub + 0] += c0;
                hbuf[nB][4 * sub + 1] += c1;
                hbuf[nB][4 * sub + 2] += c2;
                hbuf[nB][4 * sub + 3] += c3;
            }
        }
    }
    __syncthreads();

    // ---- load W2/b2 into dead srt/rb space (saves 3.3 KB static LDS) ----
    float* sW2 = (float*)srt;            // 3072 B <= 6144 B
    float* sb2 = (float*)rb;             // 192 B <= 792 B
    for (int i = t; i < 16 * 48; i += 256) sW2[i] = W2[i];
    if (t < 48) sb2[t] = b2[t];
    __syncthreads();

    // ---- inline MLP epilogue: thread per node ----
    if (t < BKT_NODES) {
        const int gn = nb * BKT_NODES + t;
        if (gn < NN) {
            float h[16];
            const float4* A = (const float4*)(za + (long)gn * 16);
#pragma unroll
            for (int j4 = 0; j4 < 4; ++j4) {
                float4 a = A[j4];
                h[4 * j4 + 0] = tanhf(a.x + hbuf[t][4 * j4 + 0]);
                h[4 * j4 + 1] = tanhf(a.y + hbuf[t][4 * j4 + 1]);
                h[4 * j4 + 2] = tanhf(a.z + hbuf[t][4 * j4 + 2]);
                h[4 * j4 + 3] = tanhf(a.w + hbuf[t][4 * j4 + 3]);
            }

            float C[KF];
#pragma unroll
            for (int k = 0; k < KF; ++k) C[k] = sb2[k];
            for (int j = 0; j < 16; ++j) {
                const float hv = h[j];
                const float* w = &sW2[j * KF];
#pragma unroll
                for (int k = 0; k < KF; ++k) C[k] += hv * w[k];
            }

            float m = C[0];
#pragma unroll
            for (int k = 1; k < KF; ++k) m = fmaxf(m, C[k]);
            float ssum = 0.f;
#pragma unroll
            for (int k = 0; k < KF; ++k) { C[k] = expf(C[k] - m); ssum += C[k]; }
            const float inv = 1.0f / ssum;

            float4* po = (float4*)(out + (long)gn * KF);
#pragma unroll
            for (int k4 = 0; k4 < 12; ++k4)
                po[k4] = make_float4(C[4*k4] * inv, C[4*k4+1] * inv,
                                     C[4*k4+2] * inv, C[4*k4+3] * inv);
        }
    }
}

// ============== fallback path (if ws too small): unchanged ==============
__global__ __launch_bounds__(256) void scatter2_kernel(
    const float* __restrict__ x,
    const int* __restrict__ ei_pos,
    const int* __restrict__ ei_neg,
    float* acc_pos,
    float* acc_neg)
{
    const int list = blockIdx.y;
    const int* ei = list ? ei_neg : ei_pos;
    float* acc = list ? acc_neg : acc_pos;

    long t = (long)blockIdx.x * blockDim.x + threadIdx.x;
    const long total = (long)NE * 12;
    if (t >= total) return;

    int e = (int)(t / 12);
    int r = (int)(t - (long)e * 12);
    int k4 = r * 4;

    int src = ei[e];
    int dst = ei[NE + e];

    const float4 v = *(const float4*)(x + (long)src * KF + k4);
    float* p = acc + (long)dst * KF + k4;

    unsafeAtomicAdd(p + 0, v.x);
    unsafeAtomicAdd(p + 1, v.y);
    unsafeAtomicAdd(p + 2, v.z);
    unsafeAtomicAdd(p + 3, v.w);
}

// full MLP for the fallback path (xpos aliases out; reads own row before write)
__global__ __launch_bounds__(256) void mlp_softmax_kernel(
    const float* __restrict__ x,
    const float* xpos,
    const float* __restrict__ xneg,
    const float* __restrict__ W1,   // [144,16]
    const float* __restrict__ b1,
    const float* __restrict__ W2,   // [16,48]
    const float* __restrict__ b2,
    float* out)
{
    __shared__ float sW1[144 * 16];
    __shared__ float sW2[16 * 48];
    __shared__ float sb1[16];
    __shared__ float sb2[48];

    for (int i = threadIdx.x; i < 144 * 16; i += blockDim.x) sW1[i] = W1[i];
    for (int i = threadIdx.x; i < 16 * 48;  i += blockDim.x) sW2[i] = W2[i];
    if (threadIdx.x < 16) sb1[threadIdx.x] = b1[threadIdx.x];
    if (threadIdx.x < 48) sb2[threadIdx.x] = b2[threadIdx.x];
    __syncthreads();

    const int n = blockIdx.x * blockDim.x + threadIdx.x;
    if (n >= NN) return;

    float h[16];
#pragma unroll
    for (int j = 0; j < 16; ++j) h[j] = sb1[j];

    const float* srcs[3];
    srcs[0] = x    + (long)n * KF;
    srcs[1] = xpos + (long)n * KF;
    srcs[2] = xneg + (long)n * KF;

    for (int s = 0; s < 3; ++s) {
        const float* px = srcs[s];
        for (int i = 0; i < KF; ++i) {
            const float v = px[i];
            const float* w = &sW1[(s * KF + i) * 16];
#pragma unroll
            for (int j = 0; j < 16; ++j) h[j] += v * w[j];
        }
    }
#pragma unroll
    for (int j = 0; j < 16; ++j) h[j] = tanhf(h[j]);

    float C[KF];
#pragma unroll
    for (int k = 0; k < KF; ++k) C[k] = sb2[k];
    for (int j = 0; j < 16; ++j) {
        const float hv = h[j];
        const float* w = &sW2[j * KF];
#pragma unroll
        for (int k = 0; k < KF; ++k) C[k] += hv * w[k];
    }

    float m = C[0];
#pragma unroll
    for (int k = 1; k < KF; ++k) m = fmaxf(m, C[k]);
    float ssum = 0.f;
#pragma unroll
    for (int k = 0; k < KF; ++k) { C[k] = expf(C[k] - m); ssum += C[k]; }
    const float inv = 1.0f / ssum;

    float* po = out + (long)n * KF;
#pragma unroll
    for (int k = 0; k < KF; ++k) po[k] = C[k] * inv;
}

extern "C" void kernel_launch(void* const* d_in, const int* in_sizes, int n_in,
                              void* d_out, int out_size, void* d_ws, size_t ws_size,
                              hipStream_t stream)
{
    const float* x      = (const float*)d_in[0];
    const int*   ei_pos = (const int*)  d_in[1];
    const int*   ei_neg = (const int*)  d_in[2];
    const float* W1     = (const float*)d_in[3];
    const float* b1     = (const float*)d_in[4];
    const float* W2     = (const float*)d_in[5];
    const float* b2     = (const float*)d_in[6];

    float* out = (float*)d_out;

    const size_t za_bytes    = (size_t)NN * 16 * sizeof(float);               // 6.4 MB
    const size_t zh_bytes    = (size_t)(NN + 2) * 16 * sizeof(__half);        // 3.2 MB
    const size_t plist_bytes = (size_t)NPB * PACK_EPB * sizeof(unsigned);     // 12.85 MB
    const size_t offTT_bytes = (size_t)(NBKT + 2) * OTT * sizeof(unsigned short); // 1.25 MB

    // ws layout: [za | zbh | zch | plist | offTT]  (~27 MB)
    size_t off = 0;
    char* ws = (char*)d_ws;
    float*          za    = (float*)(ws + off);          off += za_bytes;
    __half*         zbh   = (__half*)(ws + off);         off += zh_bytes;
    __half*         zch   = (__half*)(ws + off);         off += zh_bytes;
    unsigned*       plist = (unsigned*)(ws + off);       off += plist_bytes;
    unsigned short* offTT = (unsigned short*)(ws + off); off += offTT_bytes;
    const size_t needed = off;

    if (ws_size >= needed) {
        pack_kernel<<<NPB, 512, 0, stream>>>(x, ei_pos, ei_neg, W1, b1, offTT, plist, za, zbh, zch);
        gather_fused_kernel<<<NBKT_PER, 256, 0, stream>>>(zbh, zch, plist, offTT, za, W2, b2, out);
    } else {
        // fallback: atomic scatter + full MLP (xpos aliases out)
        float* xpos = (float*)d_out;
        float* xneg = (float*)d_ws;      // needs 19.2 MB
        const size_t acc_bytes = (size_t)NN * KF * sizeof(float);
        hipMemsetAsync(xpos, 0, acc_bytes, stream);
        hipMemsetAsync(xneg, 0, acc_bytes, stream);
        const long total = (long)NE * 12;
        dim3 grid((unsigned)((total + 255) / 256), 2, 1);
        scatter2_kernel<<<grid, 256, 0, stream>>>(x, ei_pos, ei_neg, xpos, xneg);
        mlp_softmax_kernel<<<(NN + 255) / 256, 256, 0, stream>>>(x, xpos, xneg, W1, b1, W2, b2, out);
    }
}